// Round 5
// baseline (760.288 us; speedup 1.0000x reference)
//
#include <hip/hip_runtime.h>

#define BATCH 16
#define NQ 1024
#define NK 384
#define DIM 768
#define RED 256
#define CATD 1536

typedef __attribute__((ext_vector_type(4))) float f32x4;
typedef __attribute__((ext_vector_type(8))) short short8;

__device__ __forceinline__ short f2bf(float f) {
    unsigned u = __builtin_bit_cast(unsigned, f);
    u = (u + 0x7FFF + ((u >> 16) & 1)) >> 16;
    return (short)u;
}

#define GLOAD_LDS16(g, l) __builtin_amdgcn_global_load_lds( \
    (const __attribute__((address_space(1))) unsigned int*)(g), \
    (__attribute__((address_space(3))) unsigned int*)(l), 16, 0, 0)

// ---------------------------------------------------------------------------
// Descriptor-routed bf16 MFMA NT GEMM, 256x256 tile, BK=64, 8 waves (2Mx4N),
// double-buffered LDS (2-phase: stage(t+1) || compute(t), one barrier/K-step),
// T1 bijective XCD swizzle. M/N clamped (tiles may overhang). Up to 3 segs.
// ---------------------------------------------------------------------------
struct GemmDesc {
    const short* A; const short* B;
    float* Cf; short* Cb; const float* bias;
    int M, N, K, lda, ldb, ldcf, ldcb;
    long sA, sB, sCf, sCb;
    float scale;
    int nx, ny;     // x-tiles = ceil(N/256), y-tiles = ceil(M/256); z = batches
    int start;      // flat block offset of this segment
};

__global__ __launch_bounds__(512, 2) void gemm256(
    GemmDesc d0, GemmDesc d1, GemmDesc d2, int nseg)
{
    __shared__ short Asl[2][256 * 64];   // 64 KB
    __shared__ short Bsl[2][256 * 64];   // 64 KB

    // T1 bijective chunked swizzle over the flat grid
    unsigned lin = blockIdx.x;
    const unsigned nwg = gridDim.x;
    const unsigned qc = nwg >> 3, rc = nwg & 7;
    const unsigned xcd = lin & 7, pos = lin >> 3;
    unsigned nid = (xcd < rc ? xcd * (qc + 1) : rc * (qc + 1) + (xcd - rc) * qc) + pos;

    GemmDesc d = d0;
    if (nseg > 1 && nid >= (unsigned)d1.start) d = d1;
    if (nseg > 2 && nid >= (unsigned)d2.start) d = d2;

    unsigned r = nid - (unsigned)d.start;
    const unsigned bx = r % (unsigned)d.nx; r /= (unsigned)d.nx;
    const unsigned by = r % (unsigned)d.ny;
    const unsigned bz = r / (unsigned)d.ny;

    const short* Ab = d.A + (long)bz * d.sA;
    const short* Bb = d.B + (long)bz * d.sB;
    const int m0 = by * 256, n0 = bx * 256;
    const int M = d.M, N = d.N;
    const int tid = threadIdx.x;
    const int lane = tid & 63, wid = tid >> 6;
    const int wr = wid >> 2, wc = wid & 3;          // 2M x 4N wave grid
    const int am0 = wr * 128, bn0 = wc * 64;        // wave tile: 128 x 64
    const int lr = lane & 15, lg = lane >> 4;
    const int lda = d.lda, ldb = d.ldb;

    f32x4 acc[8][4] = {};

    auto stage = [&](int buf, int k0) {
        #pragma unroll
        for (int i = 0; i < 4; i++) {
            int e = (tid + i * 512) * 8;            // 0 .. 16383
            int rr = e >> 6, c = e & 63;
            int ra = m0 + rr; if (ra > M - 1) ra = M - 1;
            GLOAD_LDS16(Ab + (long)ra * lda + k0 + c, &Asl[buf][e]);
        }
        #pragma unroll
        for (int i = 0; i < 4; i++) {
            int e = (tid + i * 512) * 8;
            int rr = e >> 6, c = e & 63;
            int rb = n0 + rr; if (rb > N - 1) rb = N - 1;
            GLOAD_LDS16(Bb + (long)rb * ldb + k0 + c, &Bsl[buf][e]);
        }
    };
    auto compute = [&](int buf) {
        #pragma unroll
        for (int ks = 0; ks < 2; ks++) {
            short8 af[8], bfv[4];
            #pragma unroll
            for (int m = 0; m < 8; m++)
                af[m] = *(const short8*)&Asl[buf][(am0 + m * 16 + lr) * 64 + ks * 32 + lg * 8];
            #pragma unroll
            for (int n = 0; n < 4; n++)
                bfv[n] = *(const short8*)&Bsl[buf][(bn0 + n * 16 + lr) * 64 + ks * 32 + lg * 8];
            #pragma unroll
            for (int m = 0; m < 8; m++)
                #pragma unroll
                for (int n = 0; n < 4; n++)
                    acc[m][n] = __builtin_amdgcn_mfma_f32_16x16x32_bf16(
                        af[m], bfv[n], acc[m][n], 0, 0, 0);
        }
    };

    // 2-phase: stage(t+1) issued before compute(t); one vmcnt(0)+barrier per step
    const int nt = d.K >> 6;
    stage(0, 0);
    __syncthreads();
    int cur = 0;
    for (int t = 0; t < nt; ++t) {
        if (t + 1 < nt) stage(cur ^ 1, (t + 1) << 6);
        compute(cur);
        __syncthreads();
        cur ^= 1;
    }

    // epilogue
    const float scale = d.scale;
    float* Cfb = d.Cf ? d.Cf + (long)bz * d.sCf : nullptr;
    short* Cbb = d.Cb ? d.Cb + (long)bz * d.sCb : nullptr;
    const float* bias = d.bias;
    #pragma unroll
    for (int m = 0; m < 8; m++) {
        #pragma unroll
        for (int n = 0; n < 4; n++) {
            int col = n0 + bn0 + n * 16 + lr;
            if (col >= N) continue;
            float bv = bias ? bias[col] : 0.f;
            #pragma unroll
            for (int j = 0; j < 4; j++) {
                int row = m0 + am0 + m * 16 + lg * 4 + j;
                if (row >= M) continue;
                float v = acc[m][n][j] * scale + bv;
                if (Cfb) Cfb[(long)row * d.ldcf + col] = v;
                if (Cbb) Cbb[(long)row * d.ldcb + col] = f2bf(v);
            }
        }
    }
}

// ---------------- column sums over tokens (atomic partial) ----------------
__global__ __launch_bounds__(256) void colsum(
    const float* __restrict__ X, float* __restrict__ mean, int N, int chunk)
{
    int b = blockIdx.x;
    int dd = blockIdx.y * 256 + threadIdx.x;
    int n0 = blockIdx.z * chunk;
    float s = 0.f;
    for (int n = n0; n < n0 + chunk; n++)
        s += X[((long)b * N + n) * DIM + dd];
    atomicAdd(&mean[b * DIM + dd], s);
}

// ------- fused: centered bf16 row-major (Xc) + raw bf16 transpose (XT) -------
template<int N>
__global__ __launch_bounds__(256) void prep_input(
    const float* __restrict__ X, const float* __restrict__ mean,
    short* __restrict__ Xc, short* __restrict__ XT, float invN)
{
    __shared__ short tile[32][33];
    int b = blockIdx.z;
    int n0 = blockIdx.x * 32, d0 = blockIdx.y * 32;
    int tx = threadIdx.x & 31, ty = threadIdx.x >> 5;
    const float* Xb = X + (long)b * N * DIM;
    short* Xcb = Xc + (long)b * N * DIM;
    float mv = mean[b * DIM + d0 + tx] * invN;
    #pragma unroll
    for (int i = 0; i < 4; i++) {
        int n = n0 + ty + i * 8;
        float x = Xb[(long)n * DIM + d0 + tx];
        tile[ty + i * 8][tx] = f2bf(x);
        Xcb[(long)n * DIM + d0 + tx] = f2bf(x - mv);
    }
    __syncthreads();
    short* XTb = XT + (long)b * DIM * N;
    #pragma unroll
    for (int i = 0; i < 4; i++) {
        int dd = d0 + ty + i * 8;
        XTb[(long)dd * N + n0 + tx] = tile[tx][ty + i * 8];
    }
}

// ---------------- all weights -> bf16 (one launch) ----------------
struct WP { const float* p[7]; };
__global__ __launch_bounds__(256) void cvt_weights(
    WP wp, short* __restrict__ Wqb, short* __restrict__ Wkb,
    short* __restrict__ WoutB)
{
    const int WSZ = RED * DIM / 8;
    const int OSZ = DIM * CATD / 8;
    int i = blockIdx.x * 256 + threadIdx.x;
    if (i >= 6 * WSZ + OSZ) return;
    const float* src;
    short* dst;
    if (i < 6 * WSZ) {
        int w = i / WSZ, o = i - w * WSZ;
        src = wp.p[w] + (long)o * 8;
        dst = (w < 3 ? Wqb + (long)w * RED * DIM
                     : Wkb + (long)(w - 3) * RED * DIM) + (long)o * 8;
    } else {
        int o = i - 6 * WSZ;
        src = wp.p[6] + (long)o * 8;
        dst = WoutB + (long)o * 8;
    }
    const f32x4* s = (const f32x4*)src;
    f32x4 x0 = s[0], x1 = s[1];
    short8 o8;
    o8[0] = f2bf(x0[0]); o8[1] = f2bf(x0[1]); o8[2] = f2bf(x0[2]); o8[3] = f2bf(x0[3]);
    o8[4] = f2bf(x1[0]); o8[5] = f2bf(x1[1]); o8[6] = f2bf(x1[2]); o8[7] = f2bf(x1[3]);
    *(short8*)dst = o8;
}

// ---------------- softmax device body (compile-time L) ----------------
template<int L>
__device__ __forceinline__ void softmax_body(
    const float* __restrict__ p, short* __restrict__ po,
    const float* __restrict__ addv)
{
    const int tid = threadIdx.x;
    const int C = (L + 255) >> 8;
    float v[C];
    float mx = -3.0e38f;
    #pragma unroll
    for (int c = 0; c < C; c++) {
        int i = tid + c * 256;
        v[c] = (i < L) ? p[i] : -3.0e38f;
        mx = fmaxf(mx, v[c]);
    }
    __shared__ float rmax[4], rsum[4];
    #pragma unroll
    for (int o = 1; o < 64; o <<= 1) mx = fmaxf(mx, __shfl_xor(mx, o));
    if ((tid & 63) == 0) rmax[tid >> 6] = mx;
    __syncthreads();
    mx = fmaxf(fmaxf(rmax[0], rmax[1]), fmaxf(rmax[2], rmax[3]));
    float s = 0.f;
    #pragma unroll
    for (int c = 0; c < C; c++) {
        float e = __expf(v[c] - mx);
        v[c] = e;
        s += e;
    }
    #pragma unroll
    for (int o = 1; o < 64; o <<= 1) s += __shfl_xor(s, o);
    if ((tid & 63) == 0) rsum[tid >> 6] = s;
    __syncthreads();
    s = rsum[0] + rsum[1] + rsum[2] + rsum[3];
    float inv = 1.0f / s;
    if (addv) {
        #pragma unroll
        for (int c = 0; c < C; c++) {
            int i = tid + c * 256;
            if (i < L) po[i] = f2bf(v[c] * inv + addv[i]);
        }
    } else {
        #pragma unroll
        for (int c = 0; c < C; c++) {
            int i = tid + c * 256;
            if (i < L) po[i] = f2bf(v[c] * inv);
        }
    }
}

// ---- merged softmax: rows [0,B*NQ) -> P1 (L=NQ); rows [B*NQ,..) -> P3 (L=NK, +hid)
__global__ __launch_bounds__(256) void softmax_two(
    const float* __restrict__ S1, short* __restrict__ P1,
    const float* __restrict__ S3, short* __restrict__ P3,
    const float* __restrict__ hid)
{
    long row = blockIdx.x;
    if (row < (long)BATCH * NQ) {
        softmax_body<NQ>(S1 + row * NQ, P1 + row * NQ, nullptr);
    } else {
        row -= (long)BATCH * NQ;
        int b = (int)(row / NQ);
        softmax_body<NK>(S3 + row * NK, P3 + row * NK, hid + (long)b * NK);
    }
}

// ---- softmax+dot for S2: scores[row] = (softmax(S2 row)) . lw  ----
__global__ __launch_bounds__(256) void softmax_dot(
    const float* __restrict__ S2, const float* __restrict__ lw,
    float* __restrict__ scores)
{
    long row = blockIdx.x;
    const float* p = S2 + row * NK;
    const int tid = threadIdx.x;
    const int C = 2;
    float v[C];
    float mx = -3.0e38f;
    #pragma unroll
    for (int c = 0; c < C; c++) {
        int i = tid + c * 256;
        v[c] = (i < NK) ? p[i] : -3.0e38f;
        mx = fmaxf(mx, v[c]);
    }
    __shared__ float rmax[4], rsum[4], rdot[4];
    #pragma unroll
    for (int o = 1; o < 64; o <<= 1) mx = fmaxf(mx, __shfl_xor(mx, o));
    if ((tid & 63) == 0) rmax[tid >> 6] = mx;
    __syncthreads();
    mx = fmaxf(fmaxf(rmax[0], rmax[1]), fmaxf(rmax[2], rmax[3]));
    float s = 0.f, dt = 0.f;
    #pragma unroll
    for (int c = 0; c < C; c++) {
        int i = tid + c * 256;
        float e = __expf(v[c] - mx);
        s += e;
        dt += (i < NK) ? e * lw[i] : 0.f;
    }
    #pragma unroll
    for (int o = 1; o < 64; o <<= 1) { s += __shfl_xor(s, o); dt += __shfl_xor(dt, o); }
    if ((tid & 63) == 0) { rsum[tid >> 6] = s; rdot[tid >> 6] = dt; }
    __syncthreads();
    if (tid == 0) {
        s = rsum[0] + rsum[1] + rsum[2] + rsum[3];
        dt = rdot[0] + rdot[1] + rdot[2] + rdot[3];
        scores[row] = dt / s;
    }
}

// ---------------- hid[b,n] = softmax_n(scores[b,n]) ----------------
__global__ __launch_bounds__(384) void hid_softmax(
    const float* __restrict__ scores, float* __restrict__ hid)
{
    int b = blockIdx.x;
    int n = threadIdx.x;
    float s = scores[b * NK + n];
    __shared__ float red[6];
    float mx = s;
    #pragma unroll
    for (int o = 1; o < 64; o <<= 1) mx = fmaxf(mx, __shfl_xor(mx, o));
    int wid = n >> 6;
    if ((n & 63) == 0) red[wid] = mx;
    __syncthreads();
    mx = red[0];
    #pragma unroll
    for (int w = 1; w < 6; w++) mx = fmaxf(mx, red[w]);
    float e = __expf(s - mx);
    float sm = e;
    #pragma unroll
    for (int o = 1; o < 64; o <<= 1) sm += __shfl_xor(sm, o);
    __syncthreads();
    if ((n & 63) == 0) red[wid] = sm;
    __syncthreads();
    sm = 0.f;
    #pragma unroll
    for (int w = 0; w < 6; w++) sm += red[w];
    hid[b * NK + n] = e / sm;
}

extern "C" void kernel_launch(void* const* d_in, const int* in_sizes, int n_in,
                              void* d_out, int out_size, void* d_ws, size_t ws_size,
                              hipStream_t stream)
{
    const float* Qf  = (const float*)d_in[0];
    const float* If  = (const float*)d_in[1];
    const float* lw  = (const float*)d_in[14];
    const float* bout= (const float*)d_in[17];

    float* cat = (float*)d_out;                              // [B,NQ,1536]
    float* out = (float*)d_out + (long)BATCH * NQ * CATD;    // [B,NQ,768]

    char* ws = (char*)d_ws;
    size_t off = 0;
    auto alloc = [&](size_t bytes) { char* p = ws + off; off += (bytes + 255) & ~(size_t)255; return p; };

    float* S1    = (float*)alloc((size_t)BATCH * NQ * NQ * 4);
    float* S2    = (float*)alloc((size_t)BATCH * NK * NK * 4);
    float* S3    = (float*)alloc((size_t)BATCH * NQ * NK * 4);
    short* Qc    = (short*)alloc((size_t)BATCH * NQ * DIM * 2);
    short* Kc    = (short*)alloc((size_t)BATCH * NK * DIM * 2);
    short* QfT   = (short*)alloc((size_t)BATCH * NQ * DIM * 2);
    short* IfT   = (short*)alloc((size_t)BATCH * NK * DIM * 2);
    short* q_all = (short*)alloc((size_t)BATCH * NQ * 3 * RED * 2);
    short* k_all = (short*)alloc((size_t)BATCH * NK * 3 * RED * 2);
    short* P1    = (short*)alloc((size_t)BATCH * NQ * NQ * 2);
    short* P3    = (short*)alloc((size_t)BATCH * NQ * NK * 2);
    short* catbf = (short*)alloc((size_t)BATCH * NQ * CATD * 2);
    short* Wqb   = (short*)alloc((size_t)3 * RED * DIM * 2);
    short* Wkb   = (short*)alloc((size_t)3 * RED * DIM * 2);
    short* WoutB = (short*)alloc((size_t)DIM * CATD * 2);
    float* means = (float*)alloc((size_t)2 * BATCH * DIM * 4);
    float* scores= (float*)alloc((size_t)BATCH * NK * 4);
    float* hid   = (float*)alloc((size_t)BATCH * NK * 4);

    float* meanQ = means;
    float* meanK = means + BATCH * DIM;

    hipMemsetAsync(means, 0, (size_t)2 * BATCH * DIM * 4, stream);

    colsum<<<dim3(BATCH, DIM / 256, NQ / 128), 256, 0, stream>>>(Qf, meanQ, NQ, 128);
    colsum<<<dim3(BATCH, DIM / 256, NK / 128), 256, 0, stream>>>(If, meanK, NK, 128);

    prep_input<NQ><<<dim3(NQ / 32, DIM / 32, BATCH), 256, 0, stream>>>(Qf, meanQ, Qc, QfT, 1.0f / NQ);
    prep_input<NK><<<dim3(NK / 32, DIM / 32, BATCH), 256, 0, stream>>>(If, meanK, Kc, IfT, 1.0f / NK);

    {
        WP wp;
        wp.p[0] = (const float*)d_in[2];
        wp.p[1] = (const float*)d_in[4];
        wp.p[2] = (const float*)d_in[6];
        wp.p[3] = (const float*)d_in[8];
        wp.p[4] = (const float*)d_in[10];
        wp.p[5] = (const float*)d_in[12];
        wp.p[6] = (const float*)d_in[16];
        int total = 6 * (RED * DIM / 8) + DIM * CATD / 8;
        cvt_weights<<<(total + 255) / 256, 256, 0, stream>>>(wp, Wqb, Wkb, WoutB);
    }

    const float scale = 0.0625f; // 1/sqrt(256)
    const long sQ = (long)NQ * 3 * RED, sK = (long)NK * 3 * RED;
    GemmDesc z = {};

    // ---- merged projections: Qc.Wqb^T -> q_all ; Kc.Wkb^T -> k_all ----
    {
        GemmDesc dq = z, dk = z;
        dq.A = Qc; dq.B = Wqb; dq.Cb = q_all;
        dq.M = BATCH * NQ; dq.N = 3 * RED; dq.K = DIM;
        dq.lda = DIM; dq.ldb = DIM; dq.ldcb = 3 * RED;
        dq.scale = 1.0f; dq.nx = 3; dq.ny = BATCH * NQ / 256; dq.start = 0;
        dk = dq; dk.A = Kc; dk.B = Wkb; dk.Cb = k_all;
        dk.M = BATCH * NK; dk.ny = BATCH * NK / 256;
        dk.start = dq.nx * dq.ny;
        int total = dk.start + dk.nx * dk.ny;
        gemm256<<<total, 512, 0, stream>>>(dq, dk, z, 2);
    }

    // ---- merged score GEMMs: S1 = q1.q2^T/16, S2 = k1.k2^T/16, S3 = q3.k3^T/16
    {
        GemmDesc a = z, b = z, c = z;
        a.A = q_all; a.B = q_all + RED; a.Cf = S1;
        a.M = NQ; a.N = NQ; a.K = RED;
        a.lda = 3 * RED; a.ldb = 3 * RED; a.ldcf = NQ;
        a.sA = sQ; a.sB = sQ; a.sCf = (long)NQ * NQ;
        a.scale = scale; a.nx = 4; a.ny = 4; a.start = 0;
        b.A = k_all; b.B = k_all + RED; b.Cf = S2;
        b.M = NK; b.N = NK; b.K = RED;
        b.lda = 3 * RED; b.ldb = 3 * RED; b.ldcf = NK;
        b.sA = sK; b.sB = sK; b.sCf = (long)NK * NK;
        b.scale = scale; b.nx = 2; b.ny = 2;
        b.start = a.nx * a.ny * BATCH;
        c.A = q_all + 2 * RED; c.B = k_all + 2 * RED; c.Cf = S3;
        c.M = NQ; c.N = NK; c.K = RED;
        c.lda = 3 * RED; c.ldb = 3 * RED; c.ldcf = NK;
        c.sA = sQ; c.sB = sK; c.sCf = (long)NQ * NK;
        c.scale = scale; c.nx = 2; c.ny = 4;
        c.start = b.start + b.nx * b.ny * BATCH;
        int total = c.start + c.nx * c.ny * BATCH;
        gemm256<<<total, 512, 0, stream>>>(a, b, c, 3);
    }

    softmax_dot<<<BATCH * NK, 256, 0, stream>>>(S2, lw, scores);
    hid_softmax<<<BATCH, NK, 0, stream>>>(scores, hid);
    softmax_two<<<2 * BATCH * NQ, 256, 0, stream>>>(S1, P1, S3, P3, hid);

    // ---- merged PV: cat[:, :768] = P1.QfT^T ; cat[:, 768:] = P3.IfT^T (dual out)
    {
        GemmDesc p1 = z, p2 = z;
        p1.A = P1; p1.B = QfT; p1.Cf = cat; p1.Cb = catbf;
        p1.M = NQ; p1.N = DIM; p1.K = NQ;
        p1.lda = NQ; p1.ldb = NQ; p1.ldcf = CATD; p1.ldcb = CATD;
        p1.sA = (long)NQ * NQ; p1.sB = (long)DIM * NQ;
        p1.sCf = (long)NQ * CATD; p1.sCb = (long)NQ * CATD;
        p1.scale = 1.0f; p1.nx = 3; p1.ny = 4; p1.start = 0;
        p2 = p1;
        p2.A = P3; p2.B = IfT; p2.Cf = cat + DIM; p2.Cb = catbf + DIM;
        p2.K = NK; p2.lda = NK; p2.ldb = NK;
        p2.sA = (long)NQ * NK; p2.sB = (long)DIM * NK;
        p2.start = p1.nx * p1.ny * BATCH;
        int total = 2 * p1.nx * p1.ny * BATCH;
        gemm256<<<total, 512, 0, stream>>>(p1, p2, z, 2);
    }

    // ---- final: out = catbf.Wout^T + bout ----
    {
        GemmDesc f = z;
        f.A = catbf; f.B = WoutB; f.Cf = out; f.bias = bout;
        f.M = BATCH * NQ; f.N = DIM; f.K = CATD;
        f.lda = CATD; f.ldb = CATD; f.ldcf = DIM;
        f.scale = 1.0f; f.nx = 3; f.ny = BATCH * NQ / 256; f.start = 0;
        gemm256<<<f.nx * f.ny, 512, 0, stream>>>(f, z, z, 1);
    }
}

// Round 7
// 648.965 us; speedup vs baseline: 1.1715x; 1.1715x over previous
//
#include <hip/hip_runtime.h>

#define BATCH 16
#define NQ 1024
#define NK 384
#define DIM 768
#define RED 256
#define CATD 1536

typedef __attribute__((ext_vector_type(4))) float f32x4;
typedef __attribute__((ext_vector_type(8))) short short8;

__device__ __forceinline__ short f2bf(float f) {
    unsigned u = __builtin_bit_cast(unsigned, f);
    u = (u + 0x7FFF + ((u >> 16) & 1)) >> 16;
    return (short)u;
}
__device__ __forceinline__ float bf2f(short s) {
    unsigned u = ((unsigned)(unsigned short)s) << 16;
    return __builtin_bit_cast(float, u);
}

#define GLOAD_LDS16(g, l) __builtin_amdgcn_global_load_lds( \
    (const __attribute__((address_space(1))) unsigned int*)(g), \
    (__attribute__((address_space(3))) unsigned int*)(l), 16, 0, 0)

// ---------------------------------------------------------------------------
// Descriptor-routed bf16 MFMA NT GEMM (m97 structure): 128x128 tile, BK=64,
// 4 waves, single-buffered LDS (32 KB -> ~3 blocks/CU), T1 bijective XCD
// swizzle over the flat grid. Up to 3 segments per launch.
// Output: f32 (Cf, +bias) and/or bf16 (Cb), selected by pointer nullness.
// ---------------------------------------------------------------------------
struct GemmDesc {
    const short* A; const short* B;
    float* Cf; short* Cb; const float* bias;
    int K, lda, ldb, ldcf, ldcb;
    long sA, sB, sCf, sCb;
    float scale;
    int nx, ny;     // x-tiles (N/128), y-tiles (M/128); z = batches
    int start;      // flat block offset of this segment
};

__global__ __launch_bounds__(256) void gemm_routed(
    GemmDesc d0, GemmDesc d1, GemmDesc d2, int nseg)
{
    __shared__ short Asl[128 * 64];
    __shared__ short Bsl[128 * 64];

    // T1 bijective chunked swizzle
    unsigned lin = blockIdx.x;
    const unsigned nwg = gridDim.x;
    const unsigned qc = nwg >> 3, rc = nwg & 7;
    const unsigned xcd = lin & 7, pos = lin >> 3;
    unsigned nid = (xcd < rc ? xcd * (qc + 1) : rc * (qc + 1) + (xcd - rc) * qc) + pos;

    GemmDesc d = d0;
    if (nseg > 1 && nid >= (unsigned)d1.start) d = d1;
    if (nseg > 2 && nid >= (unsigned)d2.start) d = d2;

    unsigned r = nid - (unsigned)d.start;
    const unsigned bx = r % (unsigned)d.nx; r /= (unsigned)d.nx;
    const unsigned by = r % (unsigned)d.ny;
    const unsigned bz = r / (unsigned)d.ny;

    const short* Ab = d.A + (long)bz * d.sA;
    const short* Bb = d.B + (long)bz * d.sB;
    const int m0 = by * 128, n0 = bx * 128;
    const int tid = threadIdx.x;
    const int lane = tid & 63, wid = tid >> 6;
    const int am0 = (wid >> 1) * 64, bn0 = (wid & 1) * 64;
    const int lr = lane & 15, lg = lane >> 4;
    const int lda = d.lda, ldb = d.ldb;

    f32x4 acc[4][4] = {};

    for (int k0 = 0; k0 < d.K; k0 += 64) {
        #pragma unroll
        for (int i = 0; i < 4; i++) {
            int e = (tid + i * 256) * 8;
            int rr = e >> 6, c = e & 63;
            GLOAD_LDS16(Ab + (long)(m0 + rr) * lda + k0 + c, Asl + e);
        }
        #pragma unroll
        for (int i = 0; i < 4; i++) {
            int e = (tid + i * 256) * 8;
            int rr = e >> 6, c = e & 63;
            GLOAD_LDS16(Bb + (long)(n0 + rr) * ldb + k0 + c, Bsl + e);
        }
        __syncthreads();
        #pragma unroll
        for (int ks = 0; ks < 2; ks++) {
            short8 af[4], bfv[4];
            #pragma unroll
            for (int m = 0; m < 4; m++)
                af[m] = *(const short8*)&Asl[(am0 + m * 16 + lr) * 64 + ks * 32 + lg * 8];
            #pragma unroll
            for (int n = 0; n < 4; n++)
                bfv[n] = *(const short8*)&Bsl[(bn0 + n * 16 + lr) * 64 + ks * 32 + lg * 8];
            #pragma unroll
            for (int m = 0; m < 4; m++)
                #pragma unroll
                for (int n = 0; n < 4; n++)
                    acc[m][n] = __builtin_amdgcn_mfma_f32_16x16x32_bf16(
                        af[m], bfv[n], acc[m][n], 0, 0, 0);
        }
        __syncthreads();
    }

    const float scale = d.scale;
    float* Cfb = d.Cf ? d.Cf + (long)bz * d.sCf : nullptr;
    short* Cbb = d.Cb ? d.Cb + (long)bz * d.sCb : nullptr;
    if (Cfb && Cbb) {
        #pragma unroll
        for (int m = 0; m < 4; m++)
            #pragma unroll
            for (int n = 0; n < 4; n++) {
                int col = n0 + bn0 + n * 16 + lr;
                #pragma unroll
                for (int j = 0; j < 4; j++) {
                    long row = m0 + am0 + m * 16 + lg * 4 + j;
                    float v = acc[m][n][j] * scale;
                    Cfb[row * d.ldcf + col] = v;
                    Cbb[row * d.ldcb + col] = f2bf(v);
                }
            }
    } else if (Cfb) {
        const float* bias = d.bias;
        #pragma unroll
        for (int m = 0; m < 4; m++)
            #pragma unroll
            for (int n = 0; n < 4; n++) {
                int col = n0 + bn0 + n * 16 + lr;
                float bv = bias ? bias[col] : 0.f;
                #pragma unroll
                for (int j = 0; j < 4; j++) {
                    long row = m0 + am0 + m * 16 + lg * 4 + j;
                    Cfb[row * d.ldcf + col] = acc[m][n][j] * scale + bv;
                }
            }
    } else {
        #pragma unroll
        for (int m = 0; m < 4; m++)
            #pragma unroll
            for (int n = 0; n < 4; n++) {
                int col = n0 + bn0 + n * 16 + lr;
                #pragma unroll
                for (int j = 0; j < 4; j++) {
                    long row = m0 + am0 + m * 16 + lg * 4 + j;
                    Cbb[row * d.ldcb + col] = f2bf(acc[m][n][j] * scale);
                }
            }
    }
}

// ---------------- column sums over tokens (atomic partial) ----------------
__global__ __launch_bounds__(256) void colsum(
    const float* __restrict__ X, float* __restrict__ mean, int N, int chunk)
{
    int b = blockIdx.x;
    int dd = blockIdx.y * 256 + threadIdx.x;
    int n0 = blockIdx.z * chunk;
    float s = 0.f;
    for (int n = n0; n < n0 + chunk; n++)
        s += X[((long)b * N + n) * DIM + dd];
    atomicAdd(&mean[b * DIM + dd], s);
}

// ------- fused: centered bf16 row-major (Xc) + raw bf16 transpose (XT) -------
template<int N>
__global__ __launch_bounds__(256) void prep_input(
    const float* __restrict__ X, const float* __restrict__ mean,
    short* __restrict__ Xc, short* __restrict__ XT, float invN)
{
    __shared__ short tile[32][33];
    int b = blockIdx.z;
    int n0 = blockIdx.x * 32, d0 = blockIdx.y * 32;
    int tx = threadIdx.x & 31, ty = threadIdx.x >> 5;
    const float* Xb = X + (long)b * N * DIM;
    short* Xcb = Xc + (long)b * N * DIM;
    float mv = mean[b * DIM + d0 + tx] * invN;
    #pragma unroll
    for (int i = 0; i < 4; i++) {
        int n = n0 + ty + i * 8;
        float x = Xb[(long)n * DIM + d0 + tx];
        tile[ty + i * 8][tx] = f2bf(x);
        Xcb[(long)n * DIM + d0 + tx] = f2bf(x - mv);
    }
    __syncthreads();
    short* XTb = XT + (long)b * DIM * N;
    #pragma unroll
    for (int i = 0; i < 4; i++) {
        int dd = d0 + ty + i * 8;
        XTb[(long)dd * N + n0 + tx] = tile[tx][ty + i * 8];
    }
}

// ---------------- all weights -> bf16 (one launch) ----------------
struct WP { const float* p[7]; };
__global__ __launch_bounds__(256) void cvt_weights(
    WP wp, short* __restrict__ Wqb, short* __restrict__ Wkb,
    short* __restrict__ WoutB)
{
    const int WSZ = RED * DIM / 8;
    const int OSZ = DIM * CATD / 8;
    int i = blockIdx.x * 256 + threadIdx.x;
    if (i >= 6 * WSZ + OSZ) return;
    const float* src;
    short* dst;
    if (i < 6 * WSZ) {
        int w = i / WSZ, o = i - w * WSZ;
        src = wp.p[w] + (long)o * 8;
        dst = (w < 3 ? Wqb + (long)w * RED * DIM
                     : Wkb + (long)(w - 3) * RED * DIM) + (long)o * 8;
    } else {
        int o = i - 6 * WSZ;
        src = wp.p[6] + (long)o * 8;
        dst = WoutB + (long)o * 8;
    }
    const f32x4* s = (const f32x4*)src;
    f32x4 x0 = s[0], x1 = s[1];
    short8 o8;
    o8[0] = f2bf(x0[0]); o8[1] = f2bf(x0[1]); o8[2] = f2bf(x0[2]); o8[3] = f2bf(x0[3]);
    o8[4] = f2bf(x1[0]); o8[5] = f2bf(x1[1]); o8[6] = f2bf(x1[2]); o8[7] = f2bf(x1[3]);
    *(short8*)dst = o8;
}

// ------- softmax body: bf16 S row -> bf16 P row IN PLACE (compile-time L) ----
template<int L>
__device__ __forceinline__ void softmax_body(
    short* __restrict__ p, const float* __restrict__ addv)
{
    const int tid = threadIdx.x;
    const int C = (L + 255) >> 8;
    float v[C];
    float mx = -3.0e38f;
    #pragma unroll
    for (int c = 0; c < C; c++) {
        int i = tid + c * 256;
        v[c] = (i < L) ? bf2f(p[i]) : -3.0e38f;
        mx = fmaxf(mx, v[c]);
    }
    __shared__ float rmax[4], rsum[4];
    #pragma unroll
    for (int o = 1; o < 64; o <<= 1) mx = fmaxf(mx, __shfl_xor(mx, o));
    if ((tid & 63) == 0) rmax[tid >> 6] = mx;
    __syncthreads();
    mx = fmaxf(fmaxf(rmax[0], rmax[1]), fmaxf(rmax[2], rmax[3]));
    float s = 0.f;
    #pragma unroll
    for (int c = 0; c < C; c++) {
        float e = __expf(v[c] - mx);
        v[c] = e;
        s += e;
    }
    #pragma unroll
    for (int o = 1; o < 64; o <<= 1) s += __shfl_xor(s, o);
    if ((tid & 63) == 0) rsum[tid >> 6] = s;
    __syncthreads();
    s = rsum[0] + rsum[1] + rsum[2] + rsum[3];
    float inv = 1.0f / s;
    if (addv) {
        #pragma unroll
        for (int c = 0; c < C; c++) {
            int i = tid + c * 256;
            if (i < L) p[i] = f2bf(v[c] * inv + addv[i]);
        }
    } else {
        #pragma unroll
        for (int c = 0; c < C; c++) {
            int i = tid + c * 256;
            if (i < L) p[i] = f2bf(v[c] * inv);
        }
    }
}

// ---- merged softmax (in place): rows [0,B*NQ) -> S1 (L=NQ); rest -> S3 (L=NK,+hid)
__global__ __launch_bounds__(256) void softmax_two(
    short* __restrict__ S1, short* __restrict__ S3,
    const float* __restrict__ hid)
{
    long row = blockIdx.x;
    if (row < (long)BATCH * NQ) {
        softmax_body<NQ>(S1 + row * NQ, nullptr);
    } else {
        row -= (long)BATCH * NQ;
        int b = (int)(row / NQ);
        softmax_body<NK>(S3 + row * NK, hid + (long)b * NK);
    }
}

// ---- softmax+dot for S2 (bf16): scores[row] = softmax(S2 row) . lw ----
__global__ __launch_bounds__(256) void softmax_dot(
    const short* __restrict__ S2, const float* __restrict__ lw,
    float* __restrict__ scores)
{
    long row = blockIdx.x;
    const short* p = S2 + row * NK;
    const int tid = threadIdx.x;
    float v[2];
    float mx = -3.0e38f;
    #pragma unroll
    for (int c = 0; c < 2; c++) {
        int i = tid + c * 256;
        v[c] = (i < NK) ? bf2f(p[i]) : -3.0e38f;
        mx = fmaxf(mx, v[c]);
    }
    __shared__ float rmax[4], rsum[4], rdot[4];
    #pragma unroll
    for (int o = 1; o < 64; o <<= 1) mx = fmaxf(mx, __shfl_xor(mx, o));
    if ((tid & 63) == 0) rmax[tid >> 6] = mx;
    __syncthreads();
    mx = fmaxf(fmaxf(rmax[0], rmax[1]), fmaxf(rmax[2], rmax[3]));
    float s = 0.f, dt = 0.f;
    #pragma unroll
    for (int c = 0; c < 2; c++) {
        int i = tid + c * 256;
        float e = __expf(v[c] - mx);
        s += e;
        dt += (i < NK) ? e * lw[i] : 0.f;
    }
    #pragma unroll
    for (int o = 1; o < 64; o <<= 1) { s += __shfl_xor(s, o); dt += __shfl_xor(dt, o); }
    if ((tid & 63) == 0) { rsum[tid >> 6] = s; rdot[tid >> 6] = dt; }
    __syncthreads();
    if (tid == 0) {
        s = rsum[0] + rsum[1] + rsum[2] + rsum[3];
        dt = rdot[0] + rdot[1] + rdot[2] + rdot[3];
        scores[row] = dt / s;
    }
}

// ---------------- hid[b,n] = softmax_n(scores[b,n]) ----------------
__global__ __launch_bounds__(384) void hid_softmax(
    const float* __restrict__ scores, float* __restrict__ hid)
{
    int b = blockIdx.x;
    int n = threadIdx.x;
    float s = scores[b * NK + n];
    __shared__ float red[6];
    float mx = s;
    #pragma unroll
    for (int o = 1; o < 64; o <<= 1) mx = fmaxf(mx, __shfl_xor(mx, o));
    int wid = n >> 6;
    if ((n & 63) == 0) red[wid] = mx;
    __syncthreads();
    mx = red[0];
    #pragma unroll
    for (int w = 1; w < 6; w++) mx = fmaxf(mx, red[w]);
    float e = __expf(s - mx);
    float sm = e;
    #pragma unroll
    for (int o = 1; o < 64; o <<= 1) sm += __shfl_xor(sm, o);
    __syncthreads();
    if ((n & 63) == 0) red[wid] = sm;
    __syncthreads();
    sm = 0.f;
    #pragma unroll
    for (int w = 0; w < 6; w++) sm += red[w];
    hid[b * NK + n] = e / sm;
}

extern "C" void kernel_launch(void* const* d_in, const int* in_sizes, int n_in,
                              void* d_out, int out_size, void* d_ws, size_t ws_size,
                              hipStream_t stream)
{
    const float* Qf  = (const float*)d_in[0];
    const float* If  = (const float*)d_in[1];
    const float* lw  = (const float*)d_in[14];
    const float* bout= (const float*)d_in[17];

    float* cat = (float*)d_out;                              // [B,NQ,1536]
    float* out = (float*)d_out + (long)BATCH * NQ * CATD;    // [B,NQ,768]

    char* ws = (char*)d_ws;
    size_t off = 0;
    auto alloc = [&](size_t bytes) { char* p = ws + off; off += (bytes + 255) & ~(size_t)255; return p; };

    short* S1    = (short*)alloc((size_t)BATCH * NQ * NQ * 2);   // bf16, becomes P1 in place
    short* S2    = (short*)alloc((size_t)BATCH * NK * NK * 2);
    short* S3    = (short*)alloc((size_t)BATCH * NQ * NK * 2);   // becomes P3 in place
    short* Qc    = (short*)alloc((size_t)BATCH * NQ * DIM * 2);
    short* Kc    = (short*)alloc((size_t)BATCH * NK * DIM * 2);
    short* QfT   = (short*)alloc((size_t)BATCH * NQ * DIM * 2);
    short* IfT   = (short*)alloc((size_t)BATCH * NK * DIM * 2);
    short* q_all = (short*)alloc((size_t)BATCH * NQ * 3 * RED * 2);
    short* k_all = (short*)alloc((size_t)BATCH * NK * 3 * RED * 2);
    short* catbf = (short*)alloc((size_t)BATCH * NQ * CATD * 2);
    short* Wqb   = (short*)alloc((size_t)3 * RED * DIM * 2);
    short* Wkb   = (short*)alloc((size_t)3 * RED * DIM * 2);
    short* WoutB = (short*)alloc((size_t)DIM * CATD * 2);
    float* means = (float*)alloc((size_t)2 * BATCH * DIM * 4);
    float* scores= (float*)alloc((size_t)BATCH * NK * 4);
    float* hid   = (float*)alloc((size_t)BATCH * NK * 4);

    float* meanQ = means;
    float* meanK = means + BATCH * DIM;

    hipMemsetAsync(means, 0, (size_t)2 * BATCH * DIM * 4, stream);

    colsum<<<dim3(BATCH, DIM / 256, NQ / 128), 256, 0, stream>>>(Qf, meanQ, NQ, 128);
    colsum<<<dim3(BATCH, DIM / 256, NK / 128), 256, 0, stream>>>(If, meanK, NK, 128);

    prep_input<NQ><<<dim3(NQ / 32, DIM / 32, BATCH), 256, 0, stream>>>(Qf, meanQ, Qc, QfT, 1.0f / NQ);
    prep_input<NK><<<dim3(NK / 32, DIM / 32, BATCH), 256, 0, stream>>>(If, meanK, Kc, IfT, 1.0f / NK);

    {
        WP wp;
        wp.p[0] = (const float*)d_in[2];
        wp.p[1] = (const float*)d_in[4];
        wp.p[2] = (const float*)d_in[6];
        wp.p[3] = (const float*)d_in[8];
        wp.p[4] = (const float*)d_in[10];
        wp.p[5] = (const float*)d_in[12];
        wp.p[6] = (const float*)d_in[16];
        int total = 6 * (RED * DIM / 8) + DIM * CATD / 8;
        cvt_weights<<<(total + 255) / 256, 256, 0, stream>>>(wp, Wqb, Wkb, WoutB);
    }

    const float scale = 0.0625f; // 1/sqrt(256)
    const long sQ = (long)NQ * 3 * RED, sK = (long)NK * 3 * RED;
    GemmDesc z = {};

    // ---- merged projections: Qc.Wqb^T -> q_all ; Kc.Wkb^T -> k_all ----
    {
        GemmDesc dq = z, dk = z;
        dq.A = Qc; dq.B = Wqb; dq.Cb = q_all;
        dq.K = DIM; dq.lda = DIM; dq.ldb = DIM; dq.ldcb = 3 * RED;
        dq.scale = 1.0f; dq.nx = 6; dq.ny = BATCH * NQ / 128; dq.start = 0;
        dk = dq; dk.A = Kc; dk.B = Wkb; dk.Cb = k_all;
        dk.ny = BATCH * NK / 128; dk.start = 6 * (BATCH * NQ / 128);
        int total = dk.start + 6 * (BATCH * NK / 128);
        gemm_routed<<<total, 256, 0, stream>>>(dq, dk, z, 2);
    }

    // ---- merged score GEMMs (bf16 out): S1=q1.q2^T/16, S2=k1.k2^T/16, S3=q3.k3^T/16
    {
        GemmDesc a = z, b = z, c = z;
        a.A = q_all; a.B = q_all + RED; a.Cb = S1;
        a.K = RED; a.lda = 3 * RED; a.ldb = 3 * RED; a.ldcb = NQ;
        a.sA = sQ; a.sB = sQ; a.sCb = (long)NQ * NQ;
        a.scale = scale; a.nx = NQ / 128; a.ny = NQ / 128; a.start = 0;
        b.A = k_all; b.B = k_all + RED; b.Cb = S2;
        b.K = RED; b.lda = 3 * RED; b.ldb = 3 * RED; b.ldcb = NK;
        b.sA = sK; b.sB = sK; b.sCb = (long)NK * NK;
        b.scale = scale; b.nx = NK / 128; b.ny = NK / 128;
        b.start = a.nx * a.ny * BATCH;
        c.A = q_all + 2 * RED; c.B = k_all + 2 * RED; c.Cb = S3;
        c.K = RED; c.lda = 3 * RED; c.ldb = 3 * RED; c.ldcb = NK;
        c.sA = sQ; c.sB = sK; c.sCb = (long)NQ * NK;
        c.scale = scale; c.nx = NK / 128; c.ny = NQ / 128;
        c.start = b.start + b.nx * b.ny * BATCH;
        int total = c.start + c.nx * c.ny * BATCH;
        gemm_routed<<<total, 256, 0, stream>>>(a, b, c, 3);
    }

    softmax_dot<<<BATCH * NK, 256, 0, stream>>>(S2, lw, scores);
    hid_softmax<<<BATCH, NK, 0, stream>>>(scores, hid);
    softmax_two<<<2 * BATCH * NQ, 256, 0, stream>>>(S1, S3, hid);   // S->P in place

    // ---- merged PV: cat[:, :768] = P1.QfT^T ; cat[:, 768:] = P3.IfT^T (dual out)
    {
        GemmDesc p1 = z, p2 = z;
        p1.A = S1; p1.B = QfT; p1.Cf = cat; p1.Cb = catbf;
        p1.K = NQ; p1.lda = NQ; p1.ldb = NQ; p1.ldcf = CATD; p1.ldcb = CATD;
        p1.sA = (long)NQ * NQ; p1.sB = (long)DIM * NQ;
        p1.sCf = (long)NQ * CATD; p1.sCb = (long)NQ * CATD;
        p1.scale = 1.0f; p1.nx = DIM / 128; p1.ny = NQ / 128; p1.start = 0;
        p2 = p1;
        p2.A = S3; p2.B = IfT; p2.Cf = cat + DIM; p2.Cb = catbf + DIM;
        p2.K = NK; p2.lda = NK; p2.ldb = NK;
        p2.sA = (long)NQ * NK; p2.sB = (long)DIM * NK;
        p2.start = p1.nx * p1.ny * BATCH;
        int total = 2 * p1.nx * p1.ny * BATCH;
        gemm_routed<<<total, 256, 0, stream>>>(p1, p2, z, 2);
    }

    // ---- final: out = catbf.Wout^T + bout ----
    {
        GemmDesc f = z;
        f.A = catbf; f.B = WoutB; f.Cf = out; f.bias = bout;
        f.K = CATD; f.lda = CATD; f.ldb = CATD; f.ldcf = DIM;
        f.scale = 1.0f; f.nx = DIM / 128; f.ny = BATCH * NQ / 128; f.start = 0;
        gemm_routed<<<f.nx * f.ny, 256, 0, stream>>>(f, z, z, 1);
    }
}